// Round 1
// 702.539 us; speedup vs baseline: 1.7643x; 1.7643x over previous
//
#include <hip/hip_runtime.h>
#include <cmath>

namespace {

constexpr int B = 64, N = 5000, DIN = 64, DMID = 128, DOUT = 32, E = 80000;

typedef unsigned short u16;
typedef __attribute__((ext_vector_type(8))) short short8;
typedef __attribute__((ext_vector_type(4))) float floatx4;

#define MFMA16(a, b, c) __builtin_amdgcn_mfma_f32_16x16x32_bf16((a), (b), (c), 0, 0, 0)

__device__ __forceinline__ u16 f2bf(float f) {
  union { float f; unsigned u; } v; v.f = f;
  unsigned r = v.u + 0x7FFFu + ((v.u >> 16) & 1u);  // RNE
  return (u16)(r >> 16);
}
__device__ __forceinline__ float bf2f(u16 s) {
  union { unsigned u; float f; } v; v.u = ((unsigned)s) << 16;
  return v.f;
}
__device__ __forceinline__ float sigmoid_fast(float x) {
  return __builtin_amdgcn_rcpf(1.f + __expf(-x));   // saturates cleanly at +-inf
}
__device__ __forceinline__ float tanh_fast(float x) {
  return fmaf(2.f, __builtin_amdgcn_rcpf(1.f + __expf(-2.f * x)), -1.f);
}

// ---------------- graph build (unchanged, verified) ----------------

__global__ void zero_kernel(int* counts, int* fill, float* msum) {
  int i = blockIdx.x * 256 + threadIdx.x;
  if (i < N) { counts[i] = 0; fill[i] = 0; }
  if (i < B * DMID) msum[i] = 0.f;
}

__global__ void count_kernel(const int* __restrict__ ei, int* counts) {
  int e = blockIdx.x * 256 + threadIdx.x;
  if (e < E) atomicAdd(&counts[ei[E + e]], 1);
}

__global__ void scan_kernel(const int* __restrict__ counts, int* rowptr, float* dis) {
  __shared__ int sdata[1024];
  const int tid = threadIdx.x;
  constexpr int CH = (N + 1023) / 1024;  // 5
  int local[CH];
  int s = 0;
  for (int i = 0; i < CH; i++) {
    int idx = tid * CH + i;
    int c = (idx < N) ? counts[idx] : 0;
    local[i] = s;
    s += c;
  }
  sdata[tid] = s;
  __syncthreads();
  for (int off = 1; off < 1024; off <<= 1) {
    int v = (tid >= off) ? sdata[tid - off] : 0;
    __syncthreads();
    sdata[tid] += v;
    __syncthreads();
  }
  int prev = (tid > 0) ? sdata[tid - 1] : 0;
  for (int i = 0; i < CH; i++) {
    int idx = tid * CH + i;
    if (idx < N) {
      rowptr[idx] = prev + local[i];
      dis[idx] = rsqrtf((float)(counts[idx] + 1));  // + self loop
    }
  }
  if (tid == 1023) rowptr[N] = sdata[1023];
}

__global__ void fill_kernel(const int* __restrict__ ei, const int* __restrict__ rowptr,
                            const float* __restrict__ dis, int* fill,
                            int* csr_src, float* csr_w) {
  int e = blockIdx.x * 256 + threadIdx.x;
  if (e >= E) return;
  int r = ei[e], c = ei[E + e];
  int pos = rowptr[c] + atomicAdd(&fill[c], 1);
  csr_src[pos] = r;
  csr_w[pos] = dis[r] * dis[c];
}

// ---------------- weight packing ----------------
// Algebraic fold: gate_pre = xs @ (Wg @ Wl_low) + H @ Wl_high + (bg @ Wl_low + bl)
// B-frag convention (16x16x32): lane l holds B[k=(l>>4)*8+jj][n=l&15], jj linear.
// wcB: combined conv weights [64x128] per gate, chunk c = g*16 + kt*8 + nt (kt<2)
// whB: Wl high-half [128x128] per gate, chunk c = g*32 + kt*8 + nt (kt<4)
// bcAll[g*128+n] = bg_g @ Wl_low + bl_g

__global__ void pack_kernel(const float* Wgz, const float* Wgr, const float* Wgh,
                            const float* Wlz, const float* Wlr, const float* Wlh,
                            const float* bgz, const float* bgr, const float* bgh,
                            const float* blz, const float* blr, const float* blh,
                            u16* wcB, u16* whB, float* bcAll) {
  int t = blockIdx.x * 256 + threadIdx.x;
  const float* Wg[3] = {Wgz, Wgr, Wgh};
  const float* Wl[3] = {Wlz, Wlr, Wlh};
  const float* bg[3] = {bgz, bgr, bgh};
  const float* bl[3] = {blz, blr, blh};
  if (t < 48 * 64) {
    // combined conv weights: Wc_g[k][n] = sum_j Wg_g[k][j] * Wl_g[j][n]
    int chunk = t >> 6, lane = t & 63;
    int q = lane >> 4, lm = lane & 15;
    int g = chunk >> 4, rem = chunk & 15, kt = rem >> 3, nt = rem & 7;
    int n = nt * 16 + lm;
#pragma unroll
    for (int jj = 0; jj < 8; jj++) {
      int k = kt * 32 + q * 8 + jj;   // < 64
      float acc = 0.f;
      for (int j = 0; j < DMID; j++)
        acc = fmaf(Wg[g][k * DMID + j], Wl[g][j * DMID + n], acc);
      wcB[(size_t)(chunk * 64 + lane) * 8 + jj] = f2bf(acc);
    }
  } else if (t < 48 * 64 + 96 * 64) {
    int t2 = t - 48 * 64;
    int chunk = t2 >> 6, lane = t2 & 63;
    int q = lane >> 4, lm = lane & 15;
    int g = chunk >> 5, rem = chunk & 31, kt = rem >> 3, nt = rem & 7;
    int n = nt * 16 + lm;
#pragma unroll
    for (int jj = 0; jj < 8; jj++) {
      int k = kt * 32 + q * 8 + jj;   // < 128
      whB[(size_t)t2 * 8 + jj] = f2bf(Wl[g][(DMID + k) * DMID + n]);
    }
  } else {
    int t3 = t - 48 * 64 - 96 * 64;
    if (t3 < 384) {
      int g = t3 >> 7, n = t3 & 127;
      float acc = bl[g][n];
      for (int j = 0; j < DMID; j++)
        acc = fmaf(bg[g][j], Wl[g][j * DMID + n], acc);
      bcAll[t3] = acc;
    }
  }
}

// ---------------- aggregation: xs = S @ x, bf16 out ----------------
// 16 lanes per (b,n) unit, float4 per lane, 4 independent units per wave.

__global__ __launch_bounds__(256) void agg_kernel(
    const float* __restrict__ x, const int* __restrict__ rowptr,
    const int* __restrict__ csr_src, const float* __restrict__ csr_w,
    const float* __restrict__ dis, u16* __restrict__ xs) {
  const int sub = threadIdx.x >> 4;      // 0..15
  const int l16 = threadIdx.x & 15;
  const int unit = blockIdx.x * 16 + sub;  // b*N + n
  const int b = unit / N;
  const int n = unit - b * N;
  const float* xb = x + (size_t)b * N * DIN;
  const float d = dis[n];
  float4 v = *(const float4*)(xb + (size_t)n * DIN + l16 * 4);
  const float sw = d * d;
  float ax = v.x * sw, ay = v.y * sw, az = v.z * sw, aw = v.w * sw;
  const int s1 = rowptr[n + 1];
  int p = rowptr[n];
  for (; p + 2 <= s1; p += 2) {
    int i0 = csr_src[p], i1 = csr_src[p + 1];
    float w0 = csr_w[p], w1 = csr_w[p + 1];
    float4 a0 = *(const float4*)(xb + (size_t)i0 * DIN + l16 * 4);
    float4 a1 = *(const float4*)(xb + (size_t)i1 * DIN + l16 * 4);
    ax = fmaf(a0.x, w0, ax); ay = fmaf(a0.y, w0, ay);
    az = fmaf(a0.z, w0, az); aw = fmaf(a0.w, w0, aw);
    ax = fmaf(a1.x, w1, ax); ay = fmaf(a1.y, w1, ay);
    az = fmaf(a1.z, w1, az); aw = fmaf(a1.w, w1, aw);
  }
  if (p < s1) {
    int i0 = csr_src[p];
    float w0 = csr_w[p];
    float4 a0 = *(const float4*)(xb + (size_t)i0 * DIN + l16 * 4);
    ax = fmaf(a0.x, w0, ax); ay = fmaf(a0.y, w0, ay);
    az = fmaf(a0.z, w0, az); aw = fmaf(a0.w, w0, aw);
  }
  uint2 o;
  o.x = (unsigned)f2bf(ax) | ((unsigned)f2bf(ay) << 16);
  o.y = (unsigned)f2bf(az) | ((unsigned)f2bf(aw) << 16);
  *(uint2*)(xs + (size_t)unit * DIN + l16 * 4) = o;
}

// ---------------- fused MFMA kernel ----------------
// 256 threads = 4 waves; wave w owns rows [w*16, w*16+16) of a 64-row tile.
// Per gate: acc = xs_frags @ WcB_g (K=64) + Hfrags @ WhB_g (K=128).
// LDS: XS_s 9.2 KB + H_s 17.4 KB = 26.6 KB -> 4 blocks/CU at 4 waves/SIMD.

constexpr int SH = 136;  // stride for 128-wide bf16 tiles
constexpr int SX = 72;   // stride for 64-wide bf16 tiles

__global__ __launch_bounds__(256, 4) void fused_mfma(
    const u16* __restrict__ xs, const float* __restrict__ H,
    const u16* __restrict__ wcB, const u16* __restrict__ whB,
    const float* __restrict__ bcAll,
    float* __restrict__ hnew, float* __restrict__ msum) {
  __shared__ u16 H_s[64 * SH];   // H tile bf16; overwritten in place by H*R
  __shared__ u16 XS_s[64 * SX];  // xs tile bf16

  const int tid = threadIdx.x;
  const int b = blockIdx.y;
  const int n0 = blockIdx.x * 64;
  const int lane = tid & 63, w = tid >> 6;
  const int q = lane >> 4, lm = lane & 15;
  const int w16 = w * 16;

  // ---- stage xs tile ----
#pragma unroll
  for (int i = 0; i < 2; i++) {
    int idx = i * 256 + tid;  // row(64) x seg(8)
    int row = idx >> 3, seg = idx & 7;
    uint4 v = make_uint4(0u, 0u, 0u, 0u);
    if (n0 + row < N) v = *(const uint4*)(xs + ((size_t)b * N + n0 + row) * DIN + seg * 8);
    *(uint4*)&XS_s[row * SX + seg * 8] = v;
  }
  // ---- stage H tile fp32 -> bf16 ----
#pragma unroll
  for (int i = 0; i < 8; i++) {
    int idx = i * 256 + tid;  // row(64) x seg(32)
    int row = idx >> 5, seg = idx & 31;
    float4 v = make_float4(0.f, 0.f, 0.f, 0.f);
    if (n0 + row < N) v = *(const float4*)(H + ((size_t)b * N + n0 + row) * DMID + seg * 4);
    uint2 p;
    p.x = (unsigned)f2bf(v.x) | ((unsigned)f2bf(v.y) << 16);
    p.y = (unsigned)f2bf(v.z) | ((unsigned)f2bf(v.w) << 16);
    *(uint2*)&H_s[row * SH + seg * 4] = p;
  }
  __syncthreads();

  // ---- A-frags for this wave's 16 rows ----
  short8 ax[2], ah[4];
#pragma unroll
  for (int kt = 0; kt < 2; kt++)
    ax[kt] = *(const short8*)&XS_s[(w16 + lm) * SX + kt * 32 + q * 8];
#pragma unroll
  for (int kt = 0; kt < 4; kt++)
    ah[kt] = *(const short8*)&H_s[(w16 + lm) * SH + kt * 32 + q * 8];

  // ---- r gate (full) ----
  floatx4 racc[8];
#pragma unroll
  for (int nt = 0; nt < 8; nt++) {
    floatx4 a = {0.f, 0.f, 0.f, 0.f};
#pragma unroll
    for (int kt = 0; kt < 2; kt++)
      a = MFMA16(ax[kt], *(const short8*)(wcB + (size_t)((16 + kt * 8 + nt) * 64 + lane) * 8), a);
#pragma unroll
    for (int kt = 0; kt < 4; kt++)
      a = MFMA16(ah[kt], *(const short8*)(whB + (size_t)((32 + kt * 8 + nt) * 64 + lane) * 8), a);
    float bias = bcAll[128 + nt * 16 + lm];
#pragma unroll
    for (int r = 0; r < 4; r++) racc[nt][r] = a[r] + bias;
  }

  // ---- H*R in place (own rows only); keep original H in racc regs ----
#pragma unroll
  for (int nt = 0; nt < 8; nt++)
#pragma unroll
    for (int r = 0; r < 4; r++) {
      int row = w16 + q * 4 + r, col = nt * 16 + lm;
      float h = bf2f(H_s[row * SH + col]);
      float rg = sigmoid_fast(racc[nt][r]);
      H_s[row * SH + col] = f2bf(h * rg);
      racc[nt][r] = h;  // reuse storage: racc now holds H (C layout)
    }
  __syncthreads();

  short8 ahr[4];
#pragma unroll
  for (int kt = 0; kt < 4; kt++)
    ahr[kt] = *(const short8*)&H_s[(w16 + lm) * SH + kt * 32 + q * 8];

  // ---- z & h gates per nt-tile, blend, store, mean-accumulate ----
#pragma unroll
  for (int nt = 0; nt < 8; nt++) {
    floatx4 za = {0.f, 0.f, 0.f, 0.f}, ha = {0.f, 0.f, 0.f, 0.f};
#pragma unroll
    for (int kt = 0; kt < 2; kt++) {
      za = MFMA16(ax[kt], *(const short8*)(wcB + (size_t)((0 + kt * 8 + nt) * 64 + lane) * 8), za);
      ha = MFMA16(ax[kt], *(const short8*)(wcB + (size_t)((32 + kt * 8 + nt) * 64 + lane) * 8), ha);
    }
#pragma unroll
    for (int kt = 0; kt < 4; kt++) {
      za = MFMA16(ah[kt], *(const short8*)(whB + (size_t)((0 + kt * 8 + nt) * 64 + lane) * 8), za);
      ha = MFMA16(ahr[kt], *(const short8*)(whB + (size_t)((64 + kt * 8 + nt) * 64 + lane) * 8), ha);
    }
    float zb = bcAll[nt * 16 + lm], hb = bcAll[256 + nt * 16 + lm];
    float colsum = 0.f;
#pragma unroll
    for (int r = 0; r < 4; r++) {
      int row = w16 + q * 4 + r;
      bool valid = (n0 + row) < N;
      float z = sigmoid_fast(za[r] + zb);
      float ht = tanh_fast(ha[r] + hb);
      float h = racc[nt][r];
      float hn = fmaf(z, h - ht, ht);  // z*H + (1-z)*ht
      if (valid) {
        hnew[((size_t)b * N + n0 + row) * DMID + nt * 16 + lm] = hn;
        colsum += hn;
      }
    }
    colsum += __shfl_xor(colsum, 16);
    colsum += __shfl_xor(colsum, 32);
    if (lane < 16) atomicAdd(&msum[b * DMID + nt * 16 + lane], colsum);
  }
}

// ---------------- output head ----------------

__global__ void out_kernel(const float* __restrict__ msum, const float* __restrict__ Wout,
                           const float* __restrict__ bout, float* __restrict__ y) {
  const int b = blockIdx.x;
  const int o = threadIdx.x;  // 32 threads
  __shared__ float m[DMID];
  for (int jj = o; jj < DMID; jj += 32)
    m[jj] = fmaxf(msum[b * DMID + jj] * (1.f / (float)N), 0.f);
  __syncthreads();
  float acc = bout[o];
  for (int jj = 0; jj < DMID; jj++)
    acc = fmaf(m[jj], Wout[jj * DOUT + o], acc);
  y[b * DOUT + o] = acc;
}

}  // namespace

extern "C" void kernel_launch(void* const* d_in, const int* in_sizes, int n_in,
                              void* d_out, int out_size, void* d_ws, size_t ws_size,
                              hipStream_t stream) {
  const float* x = (const float*)d_in[0];
  const int* ei = (const int*)d_in[1];
  const float* H = (const float*)d_in[2];
  const float* Wgz = (const float*)d_in[3];
  const float* bgz = (const float*)d_in[4];
  const float* Wgr = (const float*)d_in[5];
  const float* bgr = (const float*)d_in[6];
  const float* Wgh = (const float*)d_in[7];
  const float* bgh = (const float*)d_in[8];
  const float* Wlz = (const float*)d_in[9];
  const float* blz = (const float*)d_in[10];
  const float* Wlr = (const float*)d_in[11];
  const float* blr = (const float*)d_in[12];
  const float* Wlh = (const float*)d_in[13];
  const float* blh = (const float*)d_in[14];
  const float* Wout = (const float*)d_in[15];
  const float* bout = (const float*)d_in[16];

  float* y = (float*)d_out;                        // [B, DOUT]
  float* hnew = (float*)d_out + (size_t)B * DOUT;  // [B, N, DMID]

  char* p = (char*)d_ws;
  auto carve = [&](size_t bytes) {
    char* q = p;
    p += (bytes + 255) & ~size_t(255);
    return q;
  };
  int* counts = (int*)carve((size_t)N * 4);
  int* rowptr = (int*)carve((size_t)(N + 1) * 4);
  int* fill = (int*)carve((size_t)N * 4);
  int* csr_src = (int*)carve((size_t)E * 4);
  float* csr_w = (float*)carve((size_t)E * 4);
  float* dis = (float*)carve((size_t)N * 4);
  float* msum = (float*)carve((size_t)B * DMID * 4);
  u16* wcB = (u16*)carve((size_t)48 * 64 * 8 * 2);
  u16* whB = (u16*)carve((size_t)96 * 64 * 8 * 2);
  float* bcAll = (float*)carve((size_t)384 * 4);
  u16* xs = (u16*)carve((size_t)B * N * DIN * 2);  // ~41 MB

  zero_kernel<<<(B * DMID + 255) / 256, 256, 0, stream>>>(counts, fill, msum);
  pack_kernel<<<38, 256, 0, stream>>>(Wgz, Wgr, Wgh, Wlz, Wlr, Wlh,
                                      bgz, bgr, bgh, blz, blr, blh,
                                      wcB, whB, bcAll);
  count_kernel<<<(E + 255) / 256, 256, 0, stream>>>(ei, counts);
  scan_kernel<<<1, 1024, 0, stream>>>(counts, rowptr, dis);
  fill_kernel<<<(E + 255) / 256, 256, 0, stream>>>(ei, rowptr, dis, fill, csr_src, csr_w);
  agg_kernel<<<B * N / 16, 256, 0, stream>>>(x, rowptr, csr_src, csr_w, dis, xs);
  fused_mfma<<<dim3((N + 63) / 64, B), 256, 0, stream>>>(xs, H, wcB, whB, bcAll,
                                                         hnew, msum);
  out_kernel<<<B, 32, 0, stream>>>(msum, Wout, bout, y);
}